// Round 6
// baseline (356.797 us; speedup 1.0000x reference)
//
#include <hip/hip_runtime.h>

#define NHEADS 4
#define NEG_SLOPE 0.2f
#define EPS_LN 1e-5f
// slice binning: 64 nodes per slice
#define POOLCAP 1536
#define BIN_EPB 8192
#define MAX_NS 800

typedef __attribute__((ext_vector_type(8))) short bf16x8;
typedef __attribute__((ext_vector_type(4))) float f32x4;

// ---------------- CSR build (fallback path, used only if ws too small) ----------------
__global__ __launch_bounds__(256) void k_init_deg(int* __restrict__ deg, int n) {
    int i = blockIdx.x * 256 + threadIdx.x;
    if (i < n) deg[i] = 1;  // self-loop
}

__global__ __launch_bounds__(256) void k_count(const int* __restrict__ dst, int* __restrict__ deg, int e) {
    int i = blockIdx.x * 256 + threadIdx.x;
    if (i < e) atomicAdd(&deg[dst[i]], 1);
}

__global__ __launch_bounds__(256) void k_scan1(const int* __restrict__ deg, int* __restrict__ rs,
                                               int* __restrict__ bsum, int n) {
    __shared__ int tmp[256];
    int tx = threadIdx.x;
    int i = blockIdx.x * 256 + tx;
    int v = (i < n) ? deg[i] : 0;
    tmp[tx] = v;
    __syncthreads();
    for (int off = 1; off < 256; off <<= 1) {
        int t = (tx >= off) ? tmp[tx - off] : 0;
        __syncthreads();
        tmp[tx] += t;
        __syncthreads();
    }
    if (i < n) rs[i] = tmp[tx] - v;
    if (tx == 255) bsum[blockIdx.x] = tmp[255];
}

__global__ __launch_bounds__(256) void k_scan2(int* __restrict__ bsum, int nb) {
    __shared__ int tmp[256];
    int tx = threadIdx.x;
    int v = (tx < nb) ? bsum[tx] : 0;
    tmp[tx] = v;
    __syncthreads();
    for (int off = 1; off < 256; off <<= 1) {
        int t = (tx >= off) ? tmp[tx - off] : 0;
        __syncthreads();
        tmp[tx] += t;
        __syncthreads();
    }
    if (tx < nb) bsum[tx] = tmp[tx] - v;
}

__global__ __launch_bounds__(256) void k_scan3(int* __restrict__ rs, int* __restrict__ cur,
                                               const int* __restrict__ bsum, int n, int total) {
    int i = blockIdx.x * 256 + threadIdx.x;
    if (i < n) {
        int r = rs[i] + bsum[blockIdx.x];
        rs[i] = r;
        cur[i] = r;
    }
    if (i == 0) rs[n] = total;
}

__global__ __launch_bounds__(256) void k_scatter(const int* __restrict__ src, const int* __restrict__ dst,
                                                 int* __restrict__ cur, int* __restrict__ col, int e, int n) {
    int i = blockIdx.x * 256 + threadIdx.x;
    if (i < e + n) {
        int s, d;
        if (i < e) { s = src[i]; d = dst[i]; }
        else       { s = i - e;  d = i - e;  }
        int p = atomicAdd(&cur[d], 1);
        col[p] = s;
    }
}

__device__ __forceinline__ unsigned short cvt_bf16(float x) {
    unsigned u = __float_as_uint(x);
    u += 0x7fffu + ((u >> 16) & 1u);
    return (unsigned short)(u >> 16);
}

__device__ __forceinline__ unsigned pack2_bf16(float a, float b) {
    return (unsigned)cvt_bf16(a) | ((unsigned)cvt_bf16(b) << 16);
}

__device__ __forceinline__ float blo(unsigned u) { return __uint_as_float(u << 16); }
__device__ __forceinline__ float bhi(unsigned u) { return __uint_as_float(u & 0xffff0000u); }

// ---------------- edge binning into per-slice pools (ALL global writes coalesced) ----------------
// Mechanism (R3): random 4B stores cost a full 64B memory-side line on gfx950 (measured:
// plain/NT/atomicExch all ~59-64B per 4B scatter store). So: stage slice-major in LDS and
// write each slice's run as a dense contiguous segment. Payload 4B/edge: src | (dst&63)<<20.
__global__ __launch_bounds__(256) void k_bin(const int* __restrict__ e_src, const int* __restrict__ e_dst,
                                             int* __restrict__ cursor, unsigned* __restrict__ pool,
                                             int E, int NS) {
    __shared__ unsigned staged[BIN_EPB];       // 32 KB, slice-major packed entries
    __shared__ unsigned short st_sl[BIN_EPB];  // 16 KB, slice id per staged entry
    __shared__ int scnt[MAX_NS], sprefix[MAX_NS], scur[MAX_NS], gbase[MAX_NS];
    __shared__ int tsum[256];
    int t = threadIdx.x;
    int b0 = blockIdx.x * BIN_EPB;
    for (int s = t; s < NS; s += 256) { scnt[s] = 0; scur[s] = 0; }
    __syncthreads();
    // phase 1: count per slice
    for (int k = 0; k < BIN_EPB / 256; k++) {
        int i = b0 + k * 256 + t;
        if (i < E) atomicAdd(&scnt[e_dst[i] >> 6], 1);
    }
    __syncthreads();
    // phase 2: block-local exclusive prefix over scnt -> sprefix
    int per = (NS + 255) / 256;
    int s0 = t * per;
    int acc = 0;
    for (int k = 0; k < per; k++) { int idx = s0 + k; if (idx < NS) acc += scnt[idx]; }
    tsum[t] = acc;
    __syncthreads();
    for (int off = 1; off < 256; off <<= 1) {
        int v = (t >= off) ? tsum[t - off] : 0;
        __syncthreads();
        tsum[t] += v;
        __syncthreads();
    }
    int run = (t == 0) ? 0 : tsum[t - 1];
    for (int k = 0; k < per; k++) {
        int idx = s0 + k;
        if (idx < NS) { sprefix[idx] = run; run += scnt[idx]; }
    }
    // global segment reservation: one hot atomic per slice per block (L2-resident, cheap)
    for (int s = t; s < NS; s += 256)
        gbase[s] = atomicAdd(&cursor[s], scnt[s]);
    __syncthreads();
    // phase 3: place entries slice-major into LDS
    for (int k = 0; k < BIN_EPB / 256; k++) {
        int i = b0 + k * 256 + t;
        if (i < E) {
            int d = e_dst[i];
            int s = e_src[i];
            int sl = d >> 6;
            int p = atomicAdd(&scur[sl], 1);
            int pos = sprefix[sl] + p;
            staged[pos] = (unsigned)s | ((unsigned)(d & 63) << 20);
            st_sl[pos] = (unsigned short)sl;
        }
    }
    __syncthreads();
    // phase 4: dense coalesced write-out of each slice's segment
    int ec = E - b0; if (ec > BIN_EPB) ec = BIN_EPB; if (ec < 0) ec = 0;
    for (int i = t; i < ec; i += 256) {
        unsigned e = staged[i];
        int sl = st_sl[i];
        int off = i - sprefix[sl];
        int gp = gbase[sl] + off;
        if (gp < POOLCAP) pool[(size_t)sl * POOLCAP + gp] = e;
    }
}

// ---------------- MFMA bf16 GEMM -> bf16 h + attn coefs ----------------
// C[M,256] = A[M,K]_fp32 @ B[K,256]_fp32, bf16 MFMA, fp32 accumulate. Grid (ceil(M/128), 2).
// A staged through LDS in 64-k halves (coalesced float4 loads -> bf16 -> ds_read_b128).
template <int K>
__global__ __launch_bounds__(256) void k_gemm_gat(const float* __restrict__ A, const float* __restrict__ B,
                                                  const float* __restrict__ asrc, const float* __restrict__ adst,
                                                  unsigned short* __restrict__ Hb16, float* __restrict__ es,
                                                  float* __restrict__ ed, int M) {
    __shared__ unsigned short Bt[128][136];   // [n][k] bf16
    __shared__ unsigned short Al[128][72];    // [row][k-in-half] bf16; total LDS 53.2 KB
    int tid = threadIdx.x;
    int m0 = blockIdx.x * 128;
    int n0 = blockIdx.y * 128;
    // stage B transposed + cvt
    {
        int n = tid & 127;
        int kh = tid >> 7;
        int kbeg = kh * (K >> 1);
        int kend = kbeg + (K >> 1);
        const float* bp = B + n0 + n;
#pragma unroll 4
        for (int k = kbeg; k < kend; k += 4) {
            float b0 = bp[(size_t)k * 256];
            float b1 = bp[(size_t)(k + 1) * 256];
            float b2 = bp[(size_t)(k + 2) * 256];
            float b3 = bp[(size_t)(k + 3) * 256];
            uint2 p;
            p.x = pack2_bf16(b0, b1);
            p.y = pack2_bf16(b2, b3);
            *(uint2*)&Bt[n][k] = p;
        }
    }
    int w = tid >> 6, lane = tid & 63;
    int quad = lane >> 4, col16 = lane & 15;
    int rw = (w >> 1) * 64;
    int ch = w & 1;
    int head = blockIdx.y * 2 + ch;
    f32x4 acc[4][4] = {};
    constexpr int KH = (K > 64) ? 2 : 1;
    for (int h = 0; h < KH; h++) {
        __syncthreads();   // h=0: covers Bt staging; h>0: waves done reading Al
        // stage A half: rows 0..127, k = h*64 .. +63
#pragma unroll
        for (int it = 0; it < 8; it++) {
            int idx = it * 256 + tid;        // 2048 float4 slots
            int row = idx >> 4;
            int kq = (idx & 15) << 2;
            float4 a4 = make_float4(0.f, 0.f, 0.f, 0.f);
            int gr = m0 + row;
            if (gr < M) a4 = *(const float4*)&A[(size_t)gr * K + h * 64 + kq];
            uint2 p;
            p.x = pack2_bf16(a4.x, a4.y);
            p.y = pack2_bf16(a4.z, a4.w);
            *(uint2*)&Al[row][kq] = p;
        }
        __syncthreads();
#pragma unroll
        for (int c = 0; c < 2; c++) {
            int kbl = c * 32 + quad * 8;
            int kb = h * 64 + kbl;
            bf16x8 afr[4], bfr[4];
#pragma unroll
            for (int i = 0; i < 4; i++)
                afr[i] = *(const bf16x8*)&Al[rw + i * 16 + col16][kbl];
#pragma unroll
            for (int j = 0; j < 4; j++)
                bfr[j] = *(const bf16x8*)&Bt[ch * 64 + j * 16 + col16][kb];
#pragma unroll
            for (int i = 0; i < 4; i++)
#pragma unroll
                for (int j = 0; j < 4; j++)
                    acc[i][j] = __builtin_amdgcn_mfma_f32_16x16x32_bf16(afr[i], bfr[j], acc[i][j], 0, 0, 0);
        }
    }
    // epilogue: es/ed (fp32-exact over bf16-rounded inputs) + bf16 h stores
    int mw = m0 + rw;
    float av[4], dv[4];
#pragma unroll
    for (int j = 0; j < 4; j++) {
        av[j] = asrc[head * 64 + j * 16 + col16];
        dv[j] = adst[head * 64 + j * 16 + col16];
    }
#pragma unroll
    for (int i = 0; i < 4; i++) {
#pragma unroll
        for (int r = 0; r < 4; r++) {
            int m = mw + i * 16 + quad * 4 + r;
            float se = acc[i][0][r] * av[0] + acc[i][1][r] * av[1]
                     + acc[i][2][r] * av[2] + acc[i][3][r] * av[3];
            float sd = acc[i][0][r] * dv[0] + acc[i][1][r] * dv[1]
                     + acc[i][2][r] * dv[2] + acc[i][3][r] * dv[3];
            se += __shfl_xor(se, 1, 64); sd += __shfl_xor(sd, 1, 64);
            se += __shfl_xor(se, 2, 64); sd += __shfl_xor(sd, 2, 64);
            se += __shfl_xor(se, 4, 64); sd += __shfl_xor(sd, 4, 64);
            se += __shfl_xor(se, 8, 64); sd += __shfl_xor(sd, 8, 64);
            if (m < M) {
#pragma unroll
                for (int j = 0; j < 4; j++)
                    Hb16[(size_t)m * 256 + head * 64 + j * 16 + col16] = cvt_bf16(acc[i][j][r]);
                if (col16 == 0) { es[m * 4 + head] = se; ed[m * 4 + head] = sd; }
            }
        }
    }
}

// ---------------- MFMA bf16 GEMM with bias, fp32 out (output projection) ----------------
__global__ __launch_bounds__(256) void k_gemm(const float* __restrict__ A, const float* __restrict__ B,
                                              const float* __restrict__ bias, float* __restrict__ C,
                                              int M, int Nn, int K) {
    __shared__ unsigned short Al[128][72];
    __shared__ unsigned short Bt[128][72];
    int tid = threadIdx.x;
    int m0 = blockIdx.x * 128;
    {
        int n = tid & 127;
        int kh = tid >> 7;
        int kbeg = kh * (K >> 1);
        int kend = kbeg + (K >> 1);
        const float* bp = B + n;
        for (int k = kbeg; k < kend; k += 4) {
            float b0 = bp[(size_t)k * Nn];
            float b1 = bp[(size_t)(k + 1) * Nn];
            float b2 = bp[(size_t)(k + 2) * Nn];
            float b3 = bp[(size_t)(k + 3) * Nn];
            uint2 p;
            p.x = pack2_bf16(b0, b1);
            p.y = pack2_bf16(b2, b3);
            *(uint2*)&Bt[n][k] = p;
        }
    }
#pragma unroll
    for (int it = 0; it < 8; it++) {
        int idx = it * 256 + tid;
        int row = idx >> 4;
        int kq = (idx & 15) << 2;
        float4 a4 = make_float4(0.f, 0.f, 0.f, 0.f);
        if (m0 + row < M) a4 = *(const float4*)&A[(size_t)(m0 + row) * 64 + kq];
        uint2 p;
        p.x = pack2_bf16(a4.x, a4.y);
        p.y = pack2_bf16(a4.z, a4.w);
        *(uint2*)&Al[row][kq] = p;
    }
    __syncthreads();
    int w = tid >> 6, lane = tid & 63;
    int quad = lane >> 4, col16 = lane & 15;
    int rw = (w >> 1) * 64;
    int ch = w & 1;
    f32x4 acc[4][4] = {};
    int kc = K >> 5;
    for (int c = 0; c < kc; c++) {
        int kb = c * 32 + quad * 8;
        bf16x8 afr[4], bfr[4];
#pragma unroll
        for (int i = 0; i < 4; i++)
            afr[i] = *(const bf16x8*)&Al[rw + i * 16 + col16][kb];
#pragma unroll
        for (int j = 0; j < 4; j++)
            bfr[j] = *(const bf16x8*)&Bt[ch * 64 + j * 16 + col16][kb];
#pragma unroll
        for (int i = 0; i < 4; i++)
#pragma unroll
            for (int j = 0; j < 4; j++)
                acc[i][j] = __builtin_amdgcn_mfma_f32_16x16x32_bf16(afr[i], bfr[j], acc[i][j], 0, 0, 0);
    }
    int mw = m0 + rw;
    float bv[4];
#pragma unroll
    for (int j = 0; j < 4; j++) bv[j] = bias[ch * 64 + j * 16 + col16];
#pragma unroll
    for (int i = 0; i < 4; i++) {
#pragma unroll
        for (int r = 0; r < 4; r++) {
            int m = mw + i * 16 + quad * 4 + r;
            if (m < M) {
#pragma unroll
                for (int j = 0; j < 4; j++)
                    C[(size_t)m * Nn + ch * 64 + j * 16 + col16] = acc[i][j][r] + bv[j];
            }
        }
    }
}

// ---------------- sliced GAT aggregate: LDS re-bin + 4-deep batched 2-edge/wave uint4 gather ----------------
// R5: issue 4 pairs' (8 edges) es+Hb loads before consuming any -> ~4x memory-level
// parallelism per wave (loads are independent; es->exp->FMA chain no longer gates issue).
__global__ __launch_bounds__(512) void k_agg_sliced(const unsigned* __restrict__ Hb, const float* __restrict__ es,
                                                    const float* __restrict__ ed, const unsigned* __restrict__ pool,
                                                    const int* __restrict__ cursor, const float* __restrict__ b,
                                                    const float* __restrict__ g, const float* __restrict__ be,
                                                    float* __restrict__ out, int n) {
    __shared__ unsigned ent[POOLCAP];
    __shared__ int lcnt[64], lbase[65], lcur[64];
    int t = threadIdx.x;
    int sl = blockIdx.x;
    if (t < 64) { lcnt[t] = 0; lcur[t] = 0; }
    __syncthreads();
    int ne = cursor[sl]; if (ne > POOLCAP) ne = POOLCAP;
    for (int i = t; i < ne; i += 512)
        atomicAdd(&lcnt[pool[(size_t)sl * POOLCAP + i] >> 20], 1);
    __syncthreads();
    if (t < 64) {  // wave-parallel exclusive scan over 64 counts
        int v = lcnt[t];
        int x = v;
        for (int off = 1; off < 64; off <<= 1) {
            int y = __shfl_up(x, off, 64);
            if (t >= off) x += y;
        }
        lbase[t] = x - v;
        if (t == 63) lbase[64] = x;
    }
    __syncthreads();
    for (int i = t; i < ne; i += 512) {
        unsigned e = pool[(size_t)sl * POOLCAP + i];
        int ln = e >> 20;
        int p = atomicAdd(&lcur[ln], 1);
        ent[lbase[ln] + p] = e & 0xFFFFFu;
    }
    __syncthreads();
    int wv = t >> 6, lane = t & 63;
    int slot = lane >> 5;          // which edge of the pair
    int sub = lane & 31;           // 16B chunk within the 512B h-row
    int headL = sub >> 3;          // head owning channels 8*sub..+7
    int grp = sub & 7;             // channel-group within head
    for (int j = 0; j < 8; j++) {
        int ln = wv * 8 + j;
        int node = sl * 64 + ln;
        if (node >= n) continue;   // uniform per wave
        float edv = ed[node * 4 + headL];
        float acc0, acc1, acc2, acc3, acc4, acc5, acc6, acc7, den;
        if (slot == 0) {           // self-loop handled by slot 0 only
            float eS = es[node * 4 + headL] + edv;
            eS = fmaxf(eS, NEG_SLOPE * eS);
            float wS = __expf(eS);
            const uint4 u = *(const uint4*)&Hb[(size_t)node * 128 + (sub << 2)];
            acc0 = wS * blo(u.x); acc1 = wS * bhi(u.x);
            acc2 = wS * blo(u.y); acc3 = wS * bhi(u.y);
            acc4 = wS * blo(u.z); acc5 = wS * bhi(u.z);
            acc6 = wS * blo(u.w); acc7 = wS * bhi(u.w);
            den = wS;
        } else {
            acc0 = acc1 = acc2 = acc3 = acc4 = acc5 = acc6 = acc7 = 0.f;
            den = 0.f;
        }
        int cntn = lcnt[ln];
        int base = lbase[ln];
        int npairs = (cntn + 1) >> 1;
        int p = 0;
        // 4-deep batched main loop: all loads issued before any consumption
        for (; p + 4 <= npairs; p += 4) {
            int sx0, sx1, sx2, sx3;
            bool vx0, vx1, vx2, vx3;
            {
                int e0i = ((p + 0) << 1) + slot;
                int e1i = ((p + 1) << 1) + slot;
                int e2i = ((p + 2) << 1) + slot;
                int e3i = ((p + 3) << 1) + slot;
                vx0 = e0i < cntn; vx1 = e1i < cntn; vx2 = e2i < cntn; vx3 = e3i < cntn;
                sx0 = vx0 ? (int)ent[base + e0i] : node;
                sx1 = vx1 ? (int)ent[base + e1i] : node;
                sx2 = vx2 ? (int)ent[base + e2i] : node;
                sx3 = vx3 ? (int)ent[base + e3i] : node;
            }
            float ex0 = es[sx0 * 4 + headL];
            float ex1 = es[sx1 * 4 + headL];
            float ex2 = es[sx2 * 4 + headL];
            float ex3 = es[sx3 * 4 + headL];
            const uint4 u0 = *(const uint4*)&Hb[(size_t)sx0 * 128 + (sub << 2)];
            const uint4 u1 = *(const uint4*)&Hb[(size_t)sx1 * 128 + (sub << 2)];
            const uint4 u2 = *(const uint4*)&Hb[(size_t)sx2 * 128 + (sub << 2)];
            const uint4 u3 = *(const uint4*)&Hb[(size_t)sx3 * 128 + (sub << 2)];
            float f0 = ex0 + edv; f0 = fmaxf(f0, NEG_SLOPE * f0);
            float f1 = ex1 + edv; f1 = fmaxf(f1, NEG_SLOPE * f1);
            float f2 = ex2 + edv; f2 = fmaxf(f2, NEG_SLOPE * f2);
            float f3 = ex3 + edv; f3 = fmaxf(f3, NEG_SLOPE * f3);
            float w0 = vx0 ? __expf(f0) : 0.f;
            float w1 = vx1 ? __expf(f1) : 0.f;
            float w2 = vx2 ? __expf(f2) : 0.f;
            float w3 = vx3 ? __expf(f3) : 0.f;
            acc0 += w0 * blo(u0.x); acc1 += w0 * bhi(u0.x);
            acc2 += w0 * blo(u0.y); acc3 += w0 * bhi(u0.y);
            acc4 += w0 * blo(u0.z); acc5 += w0 * bhi(u0.z);
            acc6 += w0 * blo(u0.w); acc7 += w0 * bhi(u0.w);
            acc0 += w1 * blo(u1.x); acc1 += w1 * bhi(u1.x);
            acc2 += w1 * blo(u1.y); acc3 += w1 * bhi(u1.y);
            acc4 += w1 * blo(u1.z); acc5 += w1 * bhi(u1.z);
            acc6 += w1 * blo(u1.w); acc7 += w1 * bhi(u1.w);
            acc0 += w2 * blo(u2.x); acc1 += w2 * bhi(u2.x);
            acc2 += w2 * blo(u2.y); acc3 += w2 * bhi(u2.y);
            acc4 += w2 * blo(u2.z); acc5 += w2 * bhi(u2.z);
            acc6 += w2 * blo(u2.w); acc7 += w2 * bhi(u2.w);
            acc0 += w3 * blo(u3.x); acc1 += w3 * bhi(u3.x);
            acc2 += w3 * blo(u3.y); acc3 += w3 * bhi(u3.y);
            acc4 += w3 * blo(u3.z); acc5 += w3 * bhi(u3.z);
            acc6 += w3 * blo(u3.w); acc7 += w3 * bhi(u3.w);
            den += w0 + w1 + w2 + w3;
        }
        for (; p < npairs; p++) {
            int eidx = (p << 1) + slot;
            bool valid = eidx < cntn;
            int s = valid ? (int)ent[base + eidx] : node;
            float e0 = es[s * 4 + headL] + edv;
            e0 = fmaxf(e0, NEG_SLOPE * e0);
            float wgt = valid ? __expf(e0) : 0.f;
            const uint4 u = *(const uint4*)&Hb[(size_t)s * 128 + (sub << 2)];
            acc0 += wgt * blo(u.x); acc1 += wgt * bhi(u.x);
            acc2 += wgt * blo(u.y); acc3 += wgt * bhi(u.y);
            acc4 += wgt * blo(u.z); acc5 += wgt * bhi(u.z);
            acc6 += wgt * blo(u.w); acc7 += wgt * bhi(u.w);
            den += wgt;
        }
        // merge edge slots
        acc0 += __shfl_xor(acc0, 32, 64); acc1 += __shfl_xor(acc1, 32, 64);
        acc2 += __shfl_xor(acc2, 32, 64); acc3 += __shfl_xor(acc3, 32, 64);
        acc4 += __shfl_xor(acc4, 32, 64); acc5 += __shfl_xor(acc5, 32, 64);
        acc6 += __shfl_xor(acc6, 32, 64); acc7 += __shfl_xor(acc7, 32, 64);
        den += __shfl_xor(den, 32, 64);
        float rd = 1.f / den;
        float v0 = acc0 * rd, v1 = acc1 * rd, v2 = acc2 * rd, v3 = acc3 * rd;
        float v4 = acc4 * rd, v5 = acc5 * rd, v6 = acc6 * rd, v7 = acc7 * rd;
        // head mean: sum over heads (lane bits 3,4 of sub)
        v0 += __shfl_xor(v0, 8, 64);  v1 += __shfl_xor(v1, 8, 64);
        v2 += __shfl_xor(v2, 8, 64);  v3 += __shfl_xor(v3, 8, 64);
        v4 += __shfl_xor(v4, 8, 64);  v5 += __shfl_xor(v5, 8, 64);
        v6 += __shfl_xor(v6, 8, 64);  v7 += __shfl_xor(v7, 8, 64);
        v0 += __shfl_xor(v0, 16, 64); v1 += __shfl_xor(v1, 16, 64);
        v2 += __shfl_xor(v2, 16, 64); v3 += __shfl_xor(v3, 16, 64);
        v4 += __shfl_xor(v4, 16, 64); v5 += __shfl_xor(v5, 16, 64);
        v6 += __shfl_xor(v6, 16, 64); v7 += __shfl_xor(v7, 16, 64);
        float4 bbA = *(const float4*)&b[grp * 8];
        float4 bbB = *(const float4*)&b[grp * 8 + 4];
        v0 = 0.25f * v0 + bbA.x; v1 = 0.25f * v1 + bbA.y;
        v2 = 0.25f * v2 + bbA.z; v3 = 0.25f * v3 + bbA.w;
        v4 = 0.25f * v4 + bbB.x; v5 = 0.25f * v5 + bbB.y;
        v6 = 0.25f * v6 + bbB.z; v7 = 0.25f * v7 + bbB.w;
        float s1 = v0 + v1 + v2 + v3 + v4 + v5 + v6 + v7;
        float s2 = v0 * v0 + v1 * v1 + v2 * v2 + v3 * v3
                 + v4 * v4 + v5 * v5 + v6 * v6 + v7 * v7;
        s1 += __shfl_xor(s1, 1, 64); s2 += __shfl_xor(s2, 1, 64);
        s1 += __shfl_xor(s1, 2, 64); s2 += __shfl_xor(s2, 2, 64);
        s1 += __shfl_xor(s1, 4, 64); s2 += __shfl_xor(s2, 4, 64);
        float mean = s1 * (1.f / 64.f);
        float var = s2 * (1.f / 64.f) - mean * mean;
        float rinv = rsqrtf(var + EPS_LN);
        if (lane < 8) {            // slot 0, head 0: 8 lanes x 8 channels = full row
            float4 ggA = *(const float4*)&g[grp * 8];
            float4 ggB = *(const float4*)&g[grp * 8 + 4];
            float4 eeA = *(const float4*)&be[grp * 8];
            float4 eeB = *(const float4*)&be[grp * 8 + 4];
            float4 yA, yB;
            yA.x = fmaxf((v0 - mean) * rinv * ggA.x + eeA.x, 0.f);
            yA.y = fmaxf((v1 - mean) * rinv * ggA.y + eeA.y, 0.f);
            yA.z = fmaxf((v2 - mean) * rinv * ggA.z + eeA.z, 0.f);
            yA.w = fmaxf((v3 - mean) * rinv * ggA.w + eeA.w, 0.f);
            yB.x = fmaxf((v4 - mean) * rinv * ggB.x + eeB.x, 0.f);
            yB.y = fmaxf((v5 - mean) * rinv * ggB.y + eeB.y, 0.f);
            yB.z = fmaxf((v6 - mean) * rinv * ggB.z + eeB.z, 0.f);
            yB.w = fmaxf((v7 - mean) * rinv * ggB.w + eeB.w, 0.f);
            *(float4*)&out[(size_t)node * 64 + grp * 8] = yA;
            *(float4*)&out[(size_t)node * 64 + grp * 8 + 4] = yB;
        }
    }
}

// ---------------- CSR-fallback GAT aggregate (kept for small-ws path) ----------------
__global__ __launch_bounds__(256) void k_gat_aggregate(const unsigned* __restrict__ Hb, const float* __restrict__ es,
                                                       const float* __restrict__ ed, const int* __restrict__ rs,
                                                       const int* __restrict__ col,
                                                       const float* __restrict__ b,
                                                       const float* __restrict__ g, const float* __restrict__ be,
                                                       float* __restrict__ out, int n) {
    int node = blockIdx.x * 4 + (threadIdx.x >> 6);
    int lane = threadIdx.x & 63;
    if (node >= n) return;
    int head = lane >> 4;
    int cp = lane & 15;
    float edv = ed[node * 4 + head];
    float acc0 = 0.f, acc1 = 0.f, acc2 = 0.f, acc3 = 0.f, den = 0.f;
    int i0 = rs[node], i1 = rs[node + 1];
    int i = i0;
    for (; i + 3 < i1; i += 4) {
        int s0 = col[i], s1 = col[i + 1], s2 = col[i + 2], s3 = col[i + 3];
        float e0 = es[s0 * 4 + head];
        float e1 = es[s1 * 4 + head];
        float e2 = es[s2 * 4 + head];
        float e3 = es[s3 * 4 + head];
        uint2 u0 = *(const uint2*)&Hb[(size_t)s0 * 128 + lane * 2];
        uint2 u1 = *(const uint2*)&Hb[(size_t)s1 * 128 + lane * 2];
        uint2 u2 = *(const uint2*)&Hb[(size_t)s2 * 128 + lane * 2];
        uint2 u3 = *(const uint2*)&Hb[(size_t)s3 * 128 + lane * 2];
        e0 += edv; e1 += edv; e2 += edv; e3 += edv;
        e0 = fmaxf(e0, NEG_SLOPE * e0);
        e1 = fmaxf(e1, NEG_SLOPE * e1);
        e2 = fmaxf(e2, NEG_SLOPE * e2);
        e3 = fmaxf(e3, NEG_SLOPE * e3);
        float w0 = __expf(e0), w1 = __expf(e1), w2 = __expf(e2), w3 = __expf(e3);
        acc0 += w0 * blo(u0.x); acc1 += w0 * bhi(u0.x);
        acc2 += w0 * blo(u0.y); acc3 += w0 * bhi(u0.y);
        acc0 += w1 * blo(u1.x); acc1 += w1 * bhi(u1.x);
        acc2 += w1 * blo(u1.y); acc3 += w1 * bhi(u1.y);
        acc0 += w2 * blo(u2.x); acc1 += w2 * bhi(u2.x);
        acc2 += w2 * blo(u2.y); acc3 += w2 * bhi(u2.y);
        acc0 += w3 * blo(u3.x); acc1 += w3 * bhi(u3.x);
        acc2 += w3 * blo(u3.y); acc3 += w3 * bhi(u3.y);
        den += w0 + w1 + w2 + w3;
    }
    for (; i < i1; i++) {
        int s0 = col[i];
        float e0 = es[s0 * 4 + head] + edv;
        uint2 u0 = *(const uint2*)&Hb[(size_t)s0 * 128 + lane * 2];
        e0 = fmaxf(e0, NEG_SLOPE * e0);
        float w0 = __expf(e0);
        acc0 += w0 * blo(u0.x); acc1 += w0 * bhi(u0.x);
        acc2 += w0 * blo(u0.y); acc3 += w0 * bhi(u0.y);
        den += w0;
    }
    float rd = 1.f / den;
    float r0 = acc0 * rd, r1 = acc1 * rd, r2 = acc2 * rd, r3 = acc3 * rd;
    r0 += __shfl_xor(r0, 16, 64); r1 += __shfl_xor(r1, 16, 64);
    r2 += __shfl_xor(r2, 16, 64); r3 += __shfl_xor(r3, 16, 64);
    r0 += __shfl_xor(r0, 32, 64); r1 += __shfl_xor(r1, 32, 64);
    r2 += __shfl_xor(r2, 32, 64); r3 += __shfl_xor(r3, 32, 64);
    float4 bb = *(const float4*)&b[cp * 4];
    float v0 = 0.25f * r0 + bb.x;
    float v1 = 0.25f * r1 + bb.y;
    float v2 = 0.25f * r2 + bb.z;
    float v3 = 0.25f * r3 + bb.w;
    float s = v0 + v1 + v2 + v3;
    float q = v0 * v0 + v1 * v1 + v2 * v2 + v3 * v3;
    for (int off = 1; off < 16; off <<= 1) {
        s += __shfl_xor(s, off, 64);
        q += __shfl_xor(q, off, 64);
    }
    float mean = s * (1.f / 64.f);
    float var = q * (1.f / 64.f) - mean * mean;
    float rinv = rsqrtf(var + EPS_LN);
    float4 gg = *(const float4*)&g[cp * 4];
    float4 ee = *(const float4*)&be[cp * 4];
    if (head == 0) {
        float4 y;
        y.x = fmaxf((v0 - mean) * rinv * gg.x + ee.x, 0.f);
        y.y = fmaxf((v1 - mean) * rinv * gg.y + ee.y, 0.f);
        y.z = fmaxf((v2 - mean) * rinv * gg.z + ee.z, 0.f);
        y.w = fmaxf((v3 - mean) * rinv * gg.w + ee.w, 0.f);
        *(float4*)&out[(size_t)node * 64 + cp * 4] = y;
    }
}

// ---------------- launch ----------------
extern "C" void kernel_launch(void* const* d_in, const int* in_sizes, int n_in,
                              void* d_out, int out_size, void* d_ws, size_t ws_size,
                              hipStream_t stream) {
    const float* x     = (const float*)d_in[0];
    const int*   eidx  = (const int*)d_in[1];
    const float* W1    = (const float*)d_in[2];
    const float* asrc1 = (const float*)d_in[3];
    const float* adst1 = (const float*)d_in[4];
    const float* b1    = (const float*)d_in[5];
    const float* g1    = (const float*)d_in[6];
    const float* be1   = (const float*)d_in[7];
    const float* W2    = (const float*)d_in[8];
    const float* asrc2 = (const float*)d_in[9];
    const float* adst2 = (const float*)d_in[10];
    const float* b2    = (const float*)d_in[11];
    const float* g2    = (const float*)d_in[12];
    const float* be2   = (const float*)d_in[13];
    const float* Wo    = (const float*)d_in[14];
    const float* bo    = (const float*)d_in[15];

    const int N = in_sizes[0] / 128;
    const int E = in_sizes[1] / 2;
    const int* srcp = eidx;
    const int* dstp = eidx + E;

    // common workspace prefix
    unsigned* hb   = (unsigned*)d_ws;                       // [N*128] bf16x2 (h1, then h3)
    float* h_small = (float*)(hb + (size_t)N * 128);        // [N,64] fp32 (h2, then h4)
    float* es      = h_small + (size_t)N * 64;              // [N,4]
    float* ed      = es + (size_t)N * 4;                    // [N,4]
    int* tail      = (int*)(ed + (size_t)N * 4);

    const int nb = (N + 255) / 256;
    const int nwb = (N + 3) / 4;
    const int mt128 = (N + 127) / 128;
    const int NS = (N + 63) >> 6;

    size_t prefix_bytes = (size_t)((char*)tail - (char*)d_ws);
    size_t pool_need = prefix_bytes + (size_t)NS * POOLCAP * 4 + (size_t)NS * 4;

    unsigned* pool = (unsigned*)tail;                       // [NS*POOLCAP]
    int* cursor = (int*)(pool + (size_t)NS * POOLCAP);      // [NS]

    int* rowstart = nullptr; int* colarr = nullptr;
    bool pooled = (ws_size >= pool_need) && (NS <= MAX_NS);

    if (pooled) {
        hipMemsetAsync(cursor, 0, (size_t)NS * 4, stream);
        k_bin<<<(E + BIN_EPB - 1) / BIN_EPB, 256, 0, stream>>>(srcp, dstp, cursor, pool, E, NS);
    } else {
        int* deg  = tail;                               // [N]
        rowstart  = deg + N;                            // [N+1]
        int* cur  = rowstart + (N + 1);                 // [N]
        colarr    = cur + N;                            // [E+N]
        int* bsum = colarr + (size_t)(E + N);           // [<=256]
        k_init_deg<<<nb, 256, 0, stream>>>(deg, N);
        k_count<<<(E + 255) / 256, 256, 0, stream>>>(dstp, deg, E);
        k_scan1<<<nb, 256, 0, stream>>>(deg, rowstart, bsum, N);
        k_scan2<<<1, 256, 0, stream>>>(bsum, nb);
        k_scan3<<<nb, 256, 0, stream>>>(rowstart, cur, bsum, N, E + N);
        k_scatter<<<(E + N + 255) / 256, 256, 0, stream>>>(srcp, dstp, cur, colarr, E, N);
    }

    // layer 1
    k_gemm_gat<128><<<dim3(mt128, 2), 256, 0, stream>>>(x, W1, asrc1, adst1,
                                                        (unsigned short*)hb, es, ed, N);
    if (pooled)
        k_agg_sliced<<<NS, 512, 0, stream>>>(hb, es, ed, pool, cursor, b1, g1, be1, h_small, N);
    else
        k_gat_aggregate<<<nwb, 256, 0, stream>>>(hb, es, ed, rowstart, colarr, b1, g1, be1, h_small, N);

    // layer 2
    k_gemm_gat<64><<<dim3(mt128, 2), 256, 0, stream>>>(h_small, W2, asrc2, adst2,
                                                       (unsigned short*)hb, es, ed, N);
    if (pooled)
        k_agg_sliced<<<NS, 512, 0, stream>>>(hb, es, ed, pool, cursor, b2, g2, be2, h_small, N);
    else
        k_gat_aggregate<<<nwb, 256, 0, stream>>>(hb, es, ed, rowstart, colarr, b2, g2, be2, h_small, N);

    // output projection (MFMA, fp32 out + bias)
    k_gemm<<<mt128, 256, 0, stream>>>(h_small, Wo, bo, (float*)d_out, N, 128, 64);
}

// Round 7
// 337.437 us; speedup vs baseline: 1.0574x; 1.0574x over previous
//
#include <hip/hip_runtime.h>

#define NHEADS 4
#define NEG_SLOPE 0.2f
#define EPS_LN 1e-5f
// slice binning: 64 nodes per slice
#define POOLCAP 1536
#define BIN_EPB 8192
#define MAX_NS 800

typedef __attribute__((ext_vector_type(8))) short bf16x8;
typedef __attribute__((ext_vector_type(4))) float f32x4;

// ---------------- CSR build (fallback path, used only if ws too small) ----------------
__global__ __launch_bounds__(256) void k_init_deg(int* __restrict__ deg, int n) {
    int i = blockIdx.x * 256 + threadIdx.x;
    if (i < n) deg[i] = 1;  // self-loop
}

__global__ __launch_bounds__(256) void k_count(const int* __restrict__ dst, int* __restrict__ deg, int e) {
    int i = blockIdx.x * 256 + threadIdx.x;
    if (i < e) atomicAdd(&deg[dst[i]], 1);
}

__global__ __launch_bounds__(256) void k_scan1(const int* __restrict__ deg, int* __restrict__ rs,
                                               int* __restrict__ bsum, int n) {
    __shared__ int tmp[256];
    int tx = threadIdx.x;
    int i = blockIdx.x * 256 + tx;
    int v = (i < n) ? deg[i] : 0;
    tmp[tx] = v;
    __syncthreads();
    for (int off = 1; off < 256; off <<= 1) {
        int t = (tx >= off) ? tmp[tx - off] : 0;
        __syncthreads();
        tmp[tx] += t;
        __syncthreads();
    }
    if (i < n) rs[i] = tmp[tx] - v;
    if (tx == 255) bsum[blockIdx.x] = tmp[255];
}

__global__ __launch_bounds__(256) void k_scan2(int* __restrict__ bsum, int nb) {
    __shared__ int tmp[256];
    int tx = threadIdx.x;
    int v = (tx < nb) ? bsum[tx] : 0;
    tmp[tx] = v;
    __syncthreads();
    for (int off = 1; off < 256; off <<= 1) {
        int t = (tx >= off) ? tmp[tx - off] : 0;
        __syncthreads();
        tmp[tx] += t;
        __syncthreads();
    }
    if (tx < nb) bsum[tx] = tmp[tx] - v;
}

__global__ __launch_bounds__(256) void k_scan3(int* __restrict__ rs, int* __restrict__ cur,
                                               const int* __restrict__ bsum, int n, int total) {
    int i = blockIdx.x * 256 + threadIdx.x;
    if (i < n) {
        int r = rs[i] + bsum[blockIdx.x];
        rs[i] = r;
        cur[i] = r;
    }
    if (i == 0) rs[n] = total;
}

__global__ __launch_bounds__(256) void k_scatter(const int* __restrict__ src, const int* __restrict__ dst,
                                                 int* __restrict__ cur, int* __restrict__ col, int e, int n) {
    int i = blockIdx.x * 256 + threadIdx.x;
    if (i < e + n) {
        int s, d;
        if (i < e) { s = src[i]; d = dst[i]; }
        else       { s = i - e;  d = i - e;  }
        int p = atomicAdd(&cur[d], 1);
        col[p] = s;
    }
}

__device__ __forceinline__ unsigned short cvt_bf16(float x) {
    unsigned u = __float_as_uint(x);
    u += 0x7fffu + ((u >> 16) & 1u);
    return (unsigned short)(u >> 16);
}

__device__ __forceinline__ unsigned pack2_bf16(float a, float b) {
    return (unsigned)cvt_bf16(a) | ((unsigned)cvt_bf16(b) << 16);
}

__device__ __forceinline__ float blo(unsigned u) { return __uint_as_float(u << 16); }
__device__ __forceinline__ float bhi(unsigned u) { return __uint_as_float(u & 0xffff0000u); }

// ---------------- edge binning into per-slice pools (ALL global writes coalesced) ----------------
// Mechanism (R3): random 4B stores cost a full 64B memory-side line on gfx950. Stage
// slice-major in LDS, write each slice's run contiguously. Payload: src | (dst&63)<<20.
__global__ __launch_bounds__(256) void k_bin(const int* __restrict__ e_src, const int* __restrict__ e_dst,
                                             int* __restrict__ cursor, unsigned* __restrict__ pool,
                                             int E, int NS) {
    __shared__ unsigned staged[BIN_EPB];       // 32 KB
    __shared__ unsigned short st_sl[BIN_EPB];  // 16 KB
    __shared__ int scnt[MAX_NS], sprefix[MAX_NS], scur[MAX_NS], gbase[MAX_NS];
    __shared__ int tsum[256];
    int t = threadIdx.x;
    int b0 = blockIdx.x * BIN_EPB;
    for (int s = t; s < NS; s += 256) { scnt[s] = 0; scur[s] = 0; }
    __syncthreads();
    for (int k = 0; k < BIN_EPB / 256; k++) {
        int i = b0 + k * 256 + t;
        if (i < E) atomicAdd(&scnt[e_dst[i] >> 6], 1);
    }
    __syncthreads();
    int per = (NS + 255) / 256;
    int s0 = t * per;
    int acc = 0;
    for (int k = 0; k < per; k++) { int idx = s0 + k; if (idx < NS) acc += scnt[idx]; }
    tsum[t] = acc;
    __syncthreads();
    for (int off = 1; off < 256; off <<= 1) {
        int v = (t >= off) ? tsum[t - off] : 0;
        __syncthreads();
        tsum[t] += v;
        __syncthreads();
    }
    int run = (t == 0) ? 0 : tsum[t - 1];
    for (int k = 0; k < per; k++) {
        int idx = s0 + k;
        if (idx < NS) { sprefix[idx] = run; run += scnt[idx]; }
    }
    for (int s = t; s < NS; s += 256)
        gbase[s] = atomicAdd(&cursor[s], scnt[s]);
    __syncthreads();
    for (int k = 0; k < BIN_EPB / 256; k++) {
        int i = b0 + k * 256 + t;
        if (i < E) {
            int d = e_dst[i];
            int s = e_src[i];
            int sl = d >> 6;
            int p = atomicAdd(&scur[sl], 1);
            int pos = sprefix[sl] + p;
            staged[pos] = (unsigned)s | ((unsigned)(d & 63) << 20);
            st_sl[pos] = (unsigned short)sl;
        }
    }
    __syncthreads();
    int ec = E - b0; if (ec > BIN_EPB) ec = BIN_EPB; if (ec < 0) ec = 0;
    for (int i = t; i < ec; i += 256) {
        unsigned e = staged[i];
        int sl = st_sl[i];
        int off = i - sprefix[sl];
        int gp = gbase[sl] + off;
        if (gp < POOLCAP) pool[(size_t)sl * POOLCAP + gp] = e;
    }
}

// ---------------- MFMA bf16 GEMM -> bf16 h + attn coefs (layer-1 projection) ----------------
template <int K>
__global__ __launch_bounds__(256) void k_gemm_gat(const float* __restrict__ A, const float* __restrict__ B,
                                                  const float* __restrict__ asrc, const float* __restrict__ adst,
                                                  unsigned short* __restrict__ Hb16, float* __restrict__ es,
                                                  float* __restrict__ ed, int M) {
    __shared__ unsigned short Bt[128][136];
    __shared__ unsigned short Al[128][72];
    int tid = threadIdx.x;
    int m0 = blockIdx.x * 128;
    int n0 = blockIdx.y * 128;
    {
        int n = tid & 127;
        int kh = tid >> 7;
        int kbeg = kh * (K >> 1);
        int kend = kbeg + (K >> 1);
        const float* bp = B + n0 + n;
#pragma unroll 4
        for (int k = kbeg; k < kend; k += 4) {
            float b0 = bp[(size_t)k * 256];
            float b1 = bp[(size_t)(k + 1) * 256];
            float b2 = bp[(size_t)(k + 2) * 256];
            float b3 = bp[(size_t)(k + 3) * 256];
            uint2 p;
            p.x = pack2_bf16(b0, b1);
            p.y = pack2_bf16(b2, b3);
            *(uint2*)&Bt[n][k] = p;
        }
    }
    int w = tid >> 6, lane = tid & 63;
    int quad = lane >> 4, col16 = lane & 15;
    int rw = (w >> 1) * 64;
    int ch = w & 1;
    int head = blockIdx.y * 2 + ch;
    f32x4 acc[4][4] = {};
    constexpr int KH = (K > 64) ? 2 : 1;
    for (int h = 0; h < KH; h++) {
        __syncthreads();
#pragma unroll
        for (int it = 0; it < 8; it++) {
            int idx = it * 256 + tid;
            int row = idx >> 4;
            int kq = (idx & 15) << 2;
            float4 a4 = make_float4(0.f, 0.f, 0.f, 0.f);
            int gr = m0 + row;
            if (gr < M) a4 = *(const float4*)&A[(size_t)gr * K + h * 64 + kq];
            uint2 p;
            p.x = pack2_bf16(a4.x, a4.y);
            p.y = pack2_bf16(a4.z, a4.w);
            *(uint2*)&Al[row][kq] = p;
        }
        __syncthreads();
#pragma unroll
        for (int c = 0; c < 2; c++) {
            int kbl = c * 32 + quad * 8;
            int kb = h * 64 + kbl;
            bf16x8 afr[4], bfr[4];
#pragma unroll
            for (int i = 0; i < 4; i++)
                afr[i] = *(const bf16x8*)&Al[rw + i * 16 + col16][kbl];
#pragma unroll
            for (int j = 0; j < 4; j++)
                bfr[j] = *(const bf16x8*)&Bt[ch * 64 + j * 16 + col16][kb];
#pragma unroll
            for (int i = 0; i < 4; i++)
#pragma unroll
                for (int j = 0; j < 4; j++)
                    acc[i][j] = __builtin_amdgcn_mfma_f32_16x16x32_bf16(afr[i], bfr[j], acc[i][j], 0, 0, 0);
        }
    }
    int mw = m0 + rw;
    float av[4], dv[4];
#pragma unroll
    for (int j = 0; j < 4; j++) {
        av[j] = asrc[head * 64 + j * 16 + col16];
        dv[j] = adst[head * 64 + j * 16 + col16];
    }
#pragma unroll
    for (int i = 0; i < 4; i++) {
#pragma unroll
        for (int r = 0; r < 4; r++) {
            int m = mw + i * 16 + quad * 4 + r;
            float se = acc[i][0][r] * av[0] + acc[i][1][r] * av[1]
                     + acc[i][2][r] * av[2] + acc[i][3][r] * av[3];
            float sd = acc[i][0][r] * dv[0] + acc[i][1][r] * dv[1]
                     + acc[i][2][r] * dv[2] + acc[i][3][r] * dv[3];
            se += __shfl_xor(se, 1, 64); sd += __shfl_xor(sd, 1, 64);
            se += __shfl_xor(se, 2, 64); sd += __shfl_xor(sd, 2, 64);
            se += __shfl_xor(se, 4, 64); sd += __shfl_xor(sd, 4, 64);
            se += __shfl_xor(se, 8, 64); sd += __shfl_xor(sd, 8, 64);
            if (m < M) {
#pragma unroll
                for (int j = 0; j < 4; j++)
                    Hb16[(size_t)m * 256 + head * 64 + j * 16 + col16] = cvt_bf16(acc[i][j][r]);
                if (col16 == 0) { es[m * 4 + head] = se; ed[m * 4 + head] = sd; }
            }
        }
    }
}

// ---------------- MFMA bf16 GEMM with bias, fp32 out (fallback output projection) ----------------
__global__ __launch_bounds__(256) void k_gemm(const float* __restrict__ A, const float* __restrict__ B,
                                              const float* __restrict__ bias, float* __restrict__ C,
                                              int M, int Nn, int K) {
    __shared__ unsigned short Al[128][72];
    __shared__ unsigned short Bt[128][72];
    int tid = threadIdx.x;
    int m0 = blockIdx.x * 128;
    {
        int n = tid & 127;
        int kh = tid >> 7;
        int kbeg = kh * (K >> 1);
        int kend = kbeg + (K >> 1);
        const float* bp = B + n;
        for (int k = kbeg; k < kend; k += 4) {
            float b0 = bp[(size_t)k * Nn];
            float b1 = bp[(size_t)(k + 1) * Nn];
            float b2 = bp[(size_t)(k + 2) * Nn];
            float b3 = bp[(size_t)(k + 3) * Nn];
            uint2 p;
            p.x = pack2_bf16(b0, b1);
            p.y = pack2_bf16(b2, b3);
            *(uint2*)&Bt[n][k] = p;
        }
    }
#pragma unroll
    for (int it = 0; it < 8; it++) {
        int idx = it * 256 + tid;
        int row = idx >> 4;
        int kq = (idx & 15) << 2;
        float4 a4 = make_float4(0.f, 0.f, 0.f, 0.f);
        if (m0 + row < M) a4 = *(const float4*)&A[(size_t)(m0 + row) * 64 + kq];
        uint2 p;
        p.x = pack2_bf16(a4.x, a4.y);
        p.y = pack2_bf16(a4.z, a4.w);
        *(uint2*)&Al[row][kq] = p;
    }
    __syncthreads();
    int w = tid >> 6, lane = tid & 63;
    int quad = lane >> 4, col16 = lane & 15;
    int rw = (w >> 1) * 64;
    int ch = w & 1;
    f32x4 acc[4][4] = {};
    int kc = K >> 5;
    for (int c = 0; c < kc; c++) {
        int kb = c * 32 + quad * 8;
        bf16x8 afr[4], bfr[4];
#pragma unroll
        for (int i = 0; i < 4; i++)
            afr[i] = *(const bf16x8*)&Al[rw + i * 16 + col16][kb];
#pragma unroll
        for (int j = 0; j < 4; j++)
            bfr[j] = *(const bf16x8*)&Bt[ch * 64 + j * 16 + col16][kb];
#pragma unroll
        for (int i = 0; i < 4; i++)
#pragma unroll
            for (int j = 0; j < 4; j++)
                acc[i][j] = __builtin_amdgcn_mfma_f32_16x16x32_bf16(afr[i], bfr[j], acc[i][j], 0, 0, 0);
    }
    int mw = m0 + rw;
    float bv[4];
#pragma unroll
    for (int j = 0; j < 4; j++) bv[j] = bias[ch * 64 + j * 16 + col16];
#pragma unroll
    for (int i = 0; i < 4; i++) {
#pragma unroll
        for (int r = 0; r < 4; r++) {
            int m = mw + i * 16 + quad * 4 + r;
            if (m < M) {
#pragma unroll
                for (int j = 0; j < 4; j++)
                    C[(size_t)m * Nn + ch * 64 + j * 16 + col16] = acc[i][j][r] + bv[j];
            }
        }
    }
}

// ---------------- FUSED sliced GAT aggregate + LN + ReLU + in-block GEMM ----------------
// One block per slice of 64 nodes (8 waves x 8 nodes). Gather identical to R4 (2 edges/wave,
// uint4/lane). Post-LN y rows [64][64] stay in LDS (bf16); then the block computes
// y @ W [64xNCOL] with MFMA (Wt staged to LDS, L2-hot across blocks).
// GAT_EPI=true (NCOL=256): epilogue = es/ed dot + bf16 Hb_out (layer-2 projection fused).
// GAT_EPI=false (NCOL=128): epilogue = +bias, fp32 out_final (output projection fused).
template <int NCOL, bool GAT_EPI>
__global__ __launch_bounds__(512) void k_agg_fused(const unsigned* __restrict__ Hb_in,
                                                   const float* __restrict__ es_in,
                                                   const float* __restrict__ ed_in,
                                                   const unsigned* __restrict__ pool,
                                                   const int* __restrict__ cursor,
                                                   const float* __restrict__ bpre,
                                                   const float* __restrict__ gln,
                                                   const float* __restrict__ bln,
                                                   const float* __restrict__ W,
                                                   const float* __restrict__ asrc,
                                                   const float* __restrict__ adst,
                                                   const float* __restrict__ bout,
                                                   unsigned short* __restrict__ Hb_out,
                                                   float* __restrict__ es_out,
                                                   float* __restrict__ ed_out,
                                                   float* __restrict__ out_final, int n) {
    __shared__ unsigned ent[POOLCAP];
    __shared__ int lcnt[64], lbase[65], lcur[64];
    __shared__ unsigned short yb[64][72];        // post-LN y rows, bf16
    __shared__ unsigned short Wt[NCOL][72];      // W^T bf16 [n][k]
    int t = threadIdx.x;
    int sl = blockIdx.x;
    // zero y rows (nodes >= n must contribute 0 to the MFMA)
    for (int i = t; i < 64 * 36; i += 512) ((unsigned*)yb)[i] = 0u;
    // stage W^T (K=64 x NCOL, fp32 row-major) -> bf16 [n][k]
    {
        constexpr int TPC = 512 / NCOL;          // 2 (256) or 4 (128)
        constexpr int KPT = 64 / TPC;            // 32 or 16
        int nn = t % NCOL;
        int kh = t / NCOL;
        const float* wp = W + nn;
        for (int k = kh * KPT; k < kh * KPT + KPT; k += 4) {
            float w0 = wp[(size_t)k * NCOL];
            float w1 = wp[(size_t)(k + 1) * NCOL];
            float w2 = wp[(size_t)(k + 2) * NCOL];
            float w3 = wp[(size_t)(k + 3) * NCOL];
            uint2 p;
            p.x = pack2_bf16(w0, w1);
            p.y = pack2_bf16(w2, w3);
            *(uint2*)&Wt[nn][k] = p;
        }
    }
    if (t < 64) { lcnt[t] = 0; lcur[t] = 0; }
    __syncthreads();
    int ne = cursor[sl]; if (ne > POOLCAP) ne = POOLCAP;
    for (int i = t; i < ne; i += 512)
        atomicAdd(&lcnt[pool[(size_t)sl * POOLCAP + i] >> 20], 1);
    __syncthreads();
    if (t < 64) {  // wave-parallel exclusive scan
        int v = lcnt[t], x = v;
        for (int off = 1; off < 64; off <<= 1) {
            int y = __shfl_up(x, off, 64);
            if (t >= off) x += y;
        }
        lbase[t] = x - v;
        if (t == 63) lbase[64] = x;
    }
    __syncthreads();
    for (int i = t; i < ne; i += 512) {
        unsigned e = pool[(size_t)sl * POOLCAP + i];
        int ln = e >> 20;
        int p = atomicAdd(&lcur[ln], 1);
        ent[lbase[ln] + p] = e & 0xFFFFFu;
    }
    __syncthreads();
    int wv = t >> 6, lane = t & 63;
    int slot = lane >> 5;
    int sub = lane & 31;
    int headL = sub >> 3;
    int grp = sub & 7;
    for (int j = 0; j < 8; j++) {
        int ln = wv * 8 + j;
        int node = sl * 64 + ln;
        if (node >= n) continue;   // uniform per wave; yb row stays zero
        float edv = ed_in[node * 4 + headL];
        float acc0, acc1, acc2, acc3, acc4, acc5, acc6, acc7, den;
        if (slot == 0) {           // self-loop on slot 0 only
            float eS = es_in[node * 4 + headL] + edv;
            eS = fmaxf(eS, NEG_SLOPE * eS);
            float wS = __expf(eS);
            const uint4 u = *(const uint4*)&Hb_in[(size_t)node * 128 + (sub << 2)];
            acc0 = wS * blo(u.x); acc1 = wS * bhi(u.x);
            acc2 = wS * blo(u.y); acc3 = wS * bhi(u.y);
            acc4 = wS * blo(u.z); acc5 = wS * bhi(u.z);
            acc6 = wS * blo(u.w); acc7 = wS * bhi(u.w);
            den = wS;
        } else {
            acc0 = acc1 = acc2 = acc3 = acc4 = acc5 = acc6 = acc7 = 0.f;
            den = 0.f;
        }
        int cntn = lcnt[ln];
        int base = lbase[ln];
        int npairs = (cntn + 1) >> 1;
#pragma unroll 2
        for (int p = 0; p < npairs; p++) {
            int eidx = (p << 1) + slot;
            bool valid = eidx < cntn;
            int s = valid ? (int)ent[base + (valid ? eidx : 0)] : node;
            float e0 = es_in[s * 4 + headL] + edv;
            e0 = fmaxf(e0, NEG_SLOPE * e0);
            float wgt = valid ? __expf(e0) : 0.f;
            const uint4 u = *(const uint4*)&Hb_in[(size_t)s * 128 + (sub << 2)];
            acc0 += wgt * blo(u.x); acc1 += wgt * bhi(u.x);
            acc2 += wgt * blo(u.y); acc3 += wgt * bhi(u.y);
            acc4 += wgt * blo(u.z); acc5 += wgt * bhi(u.z);
            acc6 += wgt * blo(u.w); acc7 += wgt * bhi(u.w);
            den += wgt;
        }
        acc0 += __shfl_xor(acc0, 32, 64); acc1 += __shfl_xor(acc1, 32, 64);
        acc2 += __shfl_xor(acc2, 32, 64); acc3 += __shfl_xor(acc3, 32, 64);
        acc4 += __shfl_xor(acc4, 32, 64); acc5 += __shfl_xor(acc5, 32, 64);
        acc6 += __shfl_xor(acc6, 32, 64); acc7 += __shfl_xor(acc7, 32, 64);
        den += __shfl_xor(den, 32, 64);
        float rd = 1.f / den;
        float v0 = acc0 * rd, v1 = acc1 * rd, v2 = acc2 * rd, v3 = acc3 * rd;
        float v4 = acc4 * rd, v5 = acc5 * rd, v6 = acc6 * rd, v7 = acc7 * rd;
        v0 += __shfl_xor(v0, 8, 64);  v1 += __shfl_xor(v1, 8, 64);
        v2 += __shfl_xor(v2, 8, 64);  v3 += __shfl_xor(v3, 8, 64);
        v4 += __shfl_xor(v4, 8, 64);  v5 += __shfl_xor(v5, 8, 64);
        v6 += __shfl_xor(v6, 8, 64);  v7 += __shfl_xor(v7, 8, 64);
        v0 += __shfl_xor(v0, 16, 64); v1 += __shfl_xor(v1, 16, 64);
        v2 += __shfl_xor(v2, 16, 64); v3 += __shfl_xor(v3, 16, 64);
        v4 += __shfl_xor(v4, 16, 64); v5 += __shfl_xor(v5, 16, 64);
        v6 += __shfl_xor(v6, 16, 64); v7 += __shfl_xor(v7, 16, 64);
        float4 bbA = *(const float4*)&bpre[grp * 8];
        float4 bbB = *(const float4*)&bpre[grp * 8 + 4];
        v0 = 0.25f * v0 + bbA.x; v1 = 0.25f * v1 + bbA.y;
        v2 = 0.25f * v2 + bbA.z; v3 = 0.25f * v3 + bbA.w;
        v4 = 0.25f * v4 + bbB.x; v5 = 0.25f * v5 + bbB.y;
        v6 = 0.25f * v6 + bbB.z; v7 = 0.25f * v7 + bbB.w;
        float s1 = v0 + v1 + v2 + v3 + v4 + v5 + v6 + v7;
        float s2 = v0 * v0 + v1 * v1 + v2 * v2 + v3 * v3
                 + v4 * v4 + v5 * v5 + v6 * v6 + v7 * v7;
        s1 += __shfl_xor(s1, 1, 64); s2 += __shfl_xor(s2, 1, 64);
        s1 += __shfl_xor(s1, 2, 64); s2 += __shfl_xor(s2, 2, 64);
        s1 += __shfl_xor(s1, 4, 64); s2 += __shfl_xor(s2, 4, 64);
        float mean = s1 * (1.f / 64.f);
        float var = s2 * (1.f / 64.f) - mean * mean;
        float rinv = rsqrtf(var + EPS_LN);
        if (lane < 8) {            // slot 0, head 0: 8 lanes x 8 ch = full y row -> LDS bf16
            float4 ggA = *(const float4*)&gln[grp * 8];
            float4 ggB = *(const float4*)&gln[grp * 8 + 4];
            float4 eeA = *(const float4*)&bln[grp * 8];
            float4 eeB = *(const float4*)&bln[grp * 8 + 4];
            float y0 = fmaxf((v0 - mean) * rinv * ggA.x + eeA.x, 0.f);
            float y1 = fmaxf((v1 - mean) * rinv * ggA.y + eeA.y, 0.f);
            float y2 = fmaxf((v2 - mean) * rinv * ggA.z + eeA.z, 0.f);
            float y3 = fmaxf((v3 - mean) * rinv * ggA.w + eeA.w, 0.f);
            float y4 = fmaxf((v4 - mean) * rinv * ggB.x + eeB.x, 0.f);
            float y5 = fmaxf((v5 - mean) * rinv * ggB.y + eeB.y, 0.f);
            float y6 = fmaxf((v6 - mean) * rinv * ggB.z + eeB.z, 0.f);
            float y7 = fmaxf((v7 - mean) * rinv * ggB.w + eeB.w, 0.f);
            *(unsigned*)&yb[ln][grp * 8 + 0] = pack2_bf16(y0, y1);
            *(unsigned*)&yb[ln][grp * 8 + 2] = pack2_bf16(y2, y3);
            *(unsigned*)&yb[ln][grp * 8 + 4] = pack2_bf16(y4, y5);
            *(unsigned*)&yb[ln][grp * 8 + 6] = pack2_bf16(y6, y7);
        }
    }
    __syncthreads();
    // in-block GEMM: [64 x 64] @ [64 x NCOL], wave wv -> rows (wv&3)*16, cols (wv>>2)*NCOL/2
    constexpr int NT = NCOL / 32;
    int quad = lane >> 4, col16 = lane & 15;
    int rw4 = (wv & 3) * 16;
    int cb = (wv >> 2) * (NCOL / 2);
    f32x4 acc[NT] = {};
#pragma unroll
    for (int c = 0; c < 2; c++) {
        int kb = c * 32 + quad * 8;
        bf16x8 afr = *(const bf16x8*)&yb[rw4 + col16][kb];
#pragma unroll
        for (int jj = 0; jj < NT; jj++) {
            bf16x8 bfr = *(const bf16x8*)&Wt[cb + jj * 16 + col16][kb];
            acc[jj] = __builtin_amdgcn_mfma_f32_16x16x32_bf16(afr, bfr, acc[jj], 0, 0, 0);
        }
    }
    if constexpr (GAT_EPI) {
        // layer-2 projection epilogue: es/ed + bf16 Hb_out (same math as k_gemm_gat)
        float av[NT], dv[NT];
#pragma unroll
        for (int jj = 0; jj < NT; jj++) {
            av[jj] = asrc[cb + jj * 16 + col16];
            dv[jj] = adst[cb + jj * 16 + col16];
        }
        int headA = cb >> 6;
#pragma unroll
        for (int r = 0; r < 4; r++) {
            int node = sl * 64 + rw4 + quad * 4 + r;
            float seA = acc[0][r] * av[0] + acc[1][r] * av[1] + acc[2][r] * av[2] + acc[3][r] * av[3];
            float sdA = acc[0][r] * dv[0] + acc[1][r] * dv[1] + acc[2][r] * dv[2] + acc[3][r] * dv[3];
            float seB = acc[4][r] * av[4] + acc[5][r] * av[5] + acc[6][r] * av[6] + acc[7][r] * av[7];
            float sdB = acc[4][r] * dv[4] + acc[5][r] * dv[5] + acc[6][r] * dv[6] + acc[7][r] * dv[7];
            seA += __shfl_xor(seA, 1, 64); sdA += __shfl_xor(sdA, 1, 64);
            seB += __shfl_xor(seB, 1, 64); sdB += __shfl_xor(sdB, 1, 64);
            seA += __shfl_xor(seA, 2, 64); sdA += __shfl_xor(sdA, 2, 64);
            seB += __shfl_xor(seB, 2, 64); sdB += __shfl_xor(sdB, 2, 64);
            seA += __shfl_xor(seA, 4, 64); sdA += __shfl_xor(sdA, 4, 64);
            seB += __shfl_xor(seB, 4, 64); sdB += __shfl_xor(sdB, 4, 64);
            seA += __shfl_xor(seA, 8, 64); sdA += __shfl_xor(sdA, 8, 64);
            seB += __shfl_xor(seB, 8, 64); sdB += __shfl_xor(sdB, 8, 64);
            if (node < n) {
#pragma unroll
                for (int jj = 0; jj < NT; jj++)
                    Hb_out[(size_t)node * 256 + cb + jj * 16 + col16] = cvt_bf16(acc[jj][r]);
                if (col16 == 0) {
                    es_out[node * 4 + headA] = seA;     ed_out[node * 4 + headA] = sdA;
                    es_out[node * 4 + headA + 1] = seB; ed_out[node * 4 + headA + 1] = sdB;
                }
            }
        }
    } else {
        // output-projection epilogue: + bias, fp32 out
        float bv[NT];
#pragma unroll
        for (int jj = 0; jj < NT; jj++) bv[jj] = bout[cb + jj * 16 + col16];
#pragma unroll
        for (int r = 0; r < 4; r++) {
            int node = sl * 64 + rw4 + quad * 4 + r;
            if (node < n) {
#pragma unroll
                for (int jj = 0; jj < NT; jj++)
                    out_final[(size_t)node * NCOL + cb + jj * 16 + col16] = acc[jj][r] + bv[jj];
            }
        }
    }
}

// ---------------- unfused sliced aggregate (fallback pooled path; R4 loop) ----------------
__global__ __launch_bounds__(512) void k_agg_sliced(const unsigned* __restrict__ Hb, const float* __restrict__ es,
                                                    const float* __restrict__ ed, const unsigned* __restrict__ pool,
                                                    const int* __restrict__ cursor, const float* __restrict__ b,
                                                    const float* __restrict__ g, const float* __restrict__ be,
                                                    float* __restrict__ out, int n) {
    __shared__ unsigned ent[POOLCAP];
    __shared__ int lcnt[64], lbase[65], lcur[64];
    int t = threadIdx.x;
    int sl = blockIdx.x;
    if (t < 64) { lcnt[t] = 0; lcur[t] = 0; }
    __syncthreads();
    int ne = cursor[sl]; if (ne > POOLCAP) ne = POOLCAP;
    for (int i = t; i < ne; i += 512)
        atomicAdd(&lcnt[pool[(size_t)sl * POOLCAP + i] >> 20], 1);
    __syncthreads();
    if (t < 64) {
        int v = lcnt[t], x = v;
        for (int off = 1; off < 64; off <<= 1) {
            int y = __shfl_up(x, off, 64);
            if (t >= off) x += y;
        }
        lbase[t] = x - v;
        if (t == 63) lbase[64] = x;
    }
    __syncthreads();
    for (int i = t; i < ne; i += 512) {
        unsigned e = pool[(size_t)sl * POOLCAP + i];
        int ln = e >> 20;
        int p = atomicAdd(&lcur[ln], 1);
        ent[lbase[ln] + p] = e & 0xFFFFFu;
    }
    __syncthreads();
    int wv = t >> 6, lane = t & 63;
    int slot = lane >> 5;
    int sub = lane & 31;
    int headL = sub >> 3;
    int grp = sub & 7;
    for (int j = 0; j < 8; j++) {
        int ln = wv * 8 + j;
        int node = sl * 64 + ln;
        if (node >= n) continue;
        float edv = ed[node * 4 + headL];
        float acc0, acc1, acc2, acc3, acc4, acc5, acc6, acc7, den;
        if (slot == 0) {
            float eS = es[node * 4 + headL] + edv;
            eS = fmaxf(eS, NEG_SLOPE * eS);
            float wS = __expf(eS);
            const uint4 u = *(const uint4*)&Hb[(size_t)node * 128 + (sub << 2)];
            acc0 = wS * blo(u.x); acc1 = wS * bhi(u.x);
            acc2 = wS * blo(u.y); acc3 = wS * bhi(u.y);
            acc4 = wS * blo(u.z); acc5 = wS * bhi(u.z);
            acc6 = wS * blo(u.w); acc7 = wS * bhi(u.w);
            den = wS;
        } else {
            acc0 = acc1 = acc2 = acc3 = acc4 = acc5 = acc6 = acc7 = 0.f;
            den = 0.f;
        }
        int cntn = lcnt[ln];
        int base = lbase[ln];
        int npairs = (cntn + 1) >> 1;
#pragma unroll 2
        for (int p = 0; p < npairs; p++) {
            int eidx = (p << 1) + slot;
            bool valid = eidx < cntn;
            int s = valid ? (int)ent[base + (valid ? eidx : 0)] : node;
            float e0 = es[s * 4 + headL] + edv;
            e0 = fmaxf(e0, NEG_SLOPE * e0);
            float wgt = valid ? __expf(e0) : 0.f;
            const uint4 u = *(const uint4*)&Hb[(size_t)s * 128 + (sub << 2)];
            acc0 += wgt * blo(u.x); acc1 += wgt * bhi(u.x);
            acc2 += wgt * blo(u.y); acc3 += wgt * bhi(u.y);
            acc4 += wgt * blo(u.z); acc5 += wgt * bhi(u.z);
            acc6 += wgt * blo(u.w); acc7 += wgt * bhi(u.w);
            den += wgt;
        }
        acc0 += __shfl_xor(acc0, 32, 64); acc1 += __shfl_xor(acc1, 32, 64);
        acc2 += __shfl_xor(acc2, 32, 64); acc3 += __shfl_xor(acc3, 32, 64);
        acc4 += __shfl_xor(acc4, 32, 64); acc5 += __shfl_xor(acc5, 32, 64);
        acc6 += __shfl_xor(acc6, 32, 64); acc7 += __shfl_xor(acc7, 32, 64);
        den += __shfl_xor(den, 32, 64);
        float rd = 1.f / den;
        float v0 = acc0 * rd, v1 = acc1 * rd, v2 = acc2 * rd, v3 = acc3 * rd;
        float v4 = acc4 * rd, v5 = acc5 * rd, v6 = acc6 * rd, v7 = acc7 * rd;
        v0 += __shfl_xor(v0, 8, 64);  v1 += __shfl_xor(v1, 8, 64);
        v2 += __shfl_xor(v2, 8, 64);  v3 += __shfl_xor(v3, 8, 64);
        v4 += __shfl_xor(v4, 8, 64);  v5 += __shfl_xor(v5, 8, 64);
        v6 += __shfl_xor(v6, 8, 64);  v7 += __shfl_xor(v7, 8, 64);
        v0 += __shfl_xor(v0, 16, 64); v1 += __shfl_xor(v1, 16, 64);
        v2 += __shfl_xor(v2, 16, 64); v3 += __shfl_xor(v3, 16, 64);
        v4 += __shfl_xor(v4, 16, 64); v5 += __shfl_xor(v5, 16, 64);
        v6 += __shfl_xor(v6, 16, 64); v7 += __shfl_xor(v7, 16, 64);
        float4 bbA = *(const float4*)&b[grp * 8];
        float4 bbB = *(const float4*)&b[grp * 8 + 4];
        v0 = 0.25f * v0 + bbA.x; v1 = 0.25f * v1 + bbA.y;
        v2 = 0.25f * v2 + bbA.z; v3 = 0.25f * v3 + bbA.w;
        v4 = 0.25f * v4 + bbB.x; v5 = 0.25f * v5 + bbB.y;
        v6 = 0.25f * v6 + bbB.z; v7 = 0.25f * v7 + bbB.w;
        float s1 = v0 + v1 + v2 + v3 + v4 + v5 + v6 + v7;
        float s2 = v0 * v0 + v1 * v1 + v2 * v2 + v3 * v3
                 + v4 * v4 + v5 * v5 + v6 * v6 + v7 * v7;
        s1 += __shfl_xor(s1, 1, 64); s2 += __shfl_xor(s2, 1, 64);
        s1 += __shfl_xor(s1, 2, 64); s2 += __shfl_xor(s2, 2, 64);
        s1 += __shfl_xor(s1, 4, 64); s2 += __shfl_xor(s2, 4, 64);
        float mean = s1 * (1.f / 64.f);
        float var = s2 * (1.f / 64.f) - mean * mean;
        float rinv = rsqrtf(var + EPS_LN);
        if (lane < 8) {
            float4 ggA = *(const float4*)&g[grp * 8];
            float4 ggB = *(const float4*)&g[grp * 8 + 4];
            float4 eeA = *(const float4*)&be[grp * 8];
            float4 eeB = *(const float4*)&be[grp * 8 + 4];
            float4 yA, yB;
            yA.x = fmaxf((v0 - mean) * rinv * ggA.x + eeA.x, 0.f);
            yA.y = fmaxf((v1 - mean) * rinv * ggA.y + eeA.y, 0.f);
            yA.z = fmaxf((v2 - mean) * rinv * ggA.z + eeA.z, 0.f);
            yA.w = fmaxf((v3 - mean) * rinv * ggA.w + eeA.w, 0.f);
            yB.x = fmaxf((v4 - mean) * rinv * ggB.x + eeB.x, 0.f);
            yB.y = fmaxf((v5 - mean) * rinv * ggB.y + eeB.y, 0.f);
            yB.z = fmaxf((v6 - mean) * rinv * ggB.z + eeB.z, 0.f);
            yB.w = fmaxf((v7 - mean) * rinv * ggB.w + eeB.w, 0.f);
            *(float4*)&out[(size_t)node * 64 + grp * 8] = yA;
            *(float4*)&out[(size_t)node * 64 + grp * 8 + 4] = yB;
        }
    }
}

// ---------------- CSR-fallback GAT aggregate (kept for tiny-ws path) ----------------
__global__ __launch_bounds__(256) void k_gat_aggregate(const unsigned* __restrict__ Hb, const float* __restrict__ es,
                                                       const float* __restrict__ ed, const int* __restrict__ rs,
                                                       const int* __restrict__ col,
                                                       const float* __restrict__ b,
                                                       const float* __restrict__ g, const float* __restrict__ be,
                                                       float* __restrict__ out, int n) {
    int node = blockIdx.x * 4 + (threadIdx.x >> 6);
    int lane = threadIdx.x & 63;
    if (node >= n) return;
    int head = lane >> 4;
    int cp = lane & 15;
    float edv = ed[node * 4 + head];
    float acc0 = 0.f, acc1 = 0.f, acc2 = 0.f, acc3 = 0.f, den = 0.f;
    int i0 = rs[node], i1 = rs[node + 1];
    for (int i = i0; i < i1; i++) {
        int s0 = col[i];
        float e0 = es[s0 * 4 + head] + edv;
        uint2 u0 = *(const uint2*)&Hb[(size_t)s0 * 128 + lane * 2];
        e0 = fmaxf(e0, NEG_SLOPE * e0);
        float w0 = __expf(e0);
        acc0 += w0 * blo(u0.x); acc1 += w0 * bhi(u0.x);
        acc2 += w0 * blo(u0.y); acc3 += w0 * bhi(u0.y);
        den += w0;
    }
    float rd = 1.f / den;
    float r0 = acc0 * rd, r1 = acc1 * rd, r2 = acc2 * rd, r3 = acc3 * rd;
    r0 += __shfl_xor(r0, 16, 64); r1 += __shfl_xor(r1, 16, 64);
    r2 += __shfl_xor(r2, 16, 64); r3 += __shfl_xor(r3, 16, 64);
    r0 += __shfl_xor(r0, 32, 64); r1 += __shfl_xor(r1, 32, 64);
    r2 += __shfl_xor(r2, 32, 64); r3 += __shfl_xor(r3, 32, 64);
    float4 bb = *(const float4*)&b[cp * 4];
    float v0 = 0.25f * r0 + bb.x;
    float v1 = 0.25f * r1 + bb.y;
    float v2 = 0.25f * r2 + bb.z;
    float v3 = 0.25f * r3 + bb.w;
    float s = v0 + v1 + v2 + v3;
    float q = v0 * v0 + v1 * v1 + v2 * v2 + v3 * v3;
    for (int off = 1; off < 16; off <<= 1) {
        s += __shfl_xor(s, off, 64);
        q += __shfl_xor(q, off, 64);
    }
    float mean = s * (1.f / 64.f);
    float var = q * (1.f / 64.f) - mean * mean;
    float rinv = rsqrtf(var + EPS_LN);
    float4 gg = *(const float4*)&g[cp * 4];
    float4 ee = *(const float4*)&be[cp * 4];
    if (head == 0) {
        float4 y;
        y.x = fmaxf((v0 - mean) * rinv * gg.x + ee.x, 0.f);
        y.y = fmaxf((v1 - mean) * rinv * gg.y + ee.y, 0.f);
        y.z = fmaxf((v2 - mean) * rinv * gg.z + ee.z, 0.f);
        y.w = fmaxf((v3 - mean) * rinv * gg.w + ee.w, 0.f);
        *(float4*)&out[(size_t)node * 64 + cp * 4] = y;
    }
}

// ---------------- launch ----------------
extern "C" void kernel_launch(void* const* d_in, const int* in_sizes, int n_in,
                              void* d_out, int out_size, void* d_ws, size_t ws_size,
                              hipStream_t stream) {
    const float* x     = (const float*)d_in[0];
    const int*   eidx  = (const int*)d_in[1];
    const float* W1    = (const float*)d_in[2];
    const float* asrc1 = (const float*)d_in[3];
    const float* adst1 = (const float*)d_in[4];
    const float* b1    = (const float*)d_in[5];
    const float* g1    = (const float*)d_in[6];
    const float* be1   = (const float*)d_in[7];
    const float* W2    = (const float*)d_in[8];
    const float* asrc2 = (const float*)d_in[9];
    const float* adst2 = (const float*)d_in[10];
    const float* b2    = (const float*)d_in[11];
    const float* g2    = (const float*)d_in[12];
    const float* be2   = (const float*)d_in[13];
    const float* Wo    = (const float*)d_in[14];
    const float* bo    = (const float*)d_in[15];

    const int N = in_sizes[0] / 128;
    const int E = in_sizes[1] / 2;
    const int* srcp = eidx;
    const int* dstp = eidx + E;

    const int nb = (N + 255) / 256;
    const int nwb = (N + 3) / 4;
    const int mt128 = (N + 127) / 128;
    const int NS = (N + 63) >> 6;

    // ---------- fused path layout: h1 lives in d_out (dead before the final write) ----------
    unsigned* hb2_f = (unsigned*)d_ws;                       // [N*128] u32 (h3 bf16x2)
    float* es1_f = (float*)(hb2_f + (size_t)N * 128);        // [N,4]
    float* ed1_f = es1_f + (size_t)N * 4;
    float* es2_f = ed1_f + (size_t)N * 4;
    float* ed2_f = es2_f + (size_t)N * 4;
    unsigned* pool_f = (unsigned*)(ed2_f + (size_t)N * 4);   // [NS*POOLCAP]
    int* cursor_f = (int*)(pool_f + (size_t)NS * POOLCAP);   // [NS]
    size_t fused_need = (size_t)((char*)(cursor_f + NS) - (char*)d_ws);
    bool fused = (ws_size >= fused_need) && (NS <= MAX_NS) &&
                 ((size_t)out_size >= (size_t)N * 512);

    if (fused) {
        unsigned* hb1 = (unsigned*)d_out;   // scratch reuse; fully overwritten by final epilogue
        hipMemsetAsync(cursor_f, 0, (size_t)NS * 4, stream);
        k_bin<<<(E + BIN_EPB - 1) / BIN_EPB, 256, 0, stream>>>(srcp, dstp, cursor_f, pool_f, E, NS);
        // layer-1 projection -> h1 (in d_out), es1/ed1
        k_gemm_gat<128><<<dim3(mt128, 2), 256, 0, stream>>>(x, W1, asrc1, adst1,
                                                            (unsigned short*)hb1, es1_f, ed1_f, N);
        // agg1 + LN + ReLU + (h2 @ W2) -> h3 (hb2), es2/ed2
        k_agg_fused<256, true><<<NS, 512, 0, stream>>>(hb1, es1_f, ed1_f, pool_f, cursor_f,
                                                       b1, g1, be1, W2, asrc2, adst2, nullptr,
                                                       (unsigned short*)hb2_f, es2_f, ed2_f,
                                                       nullptr, N);
        // agg2 + LN + ReLU + (h4 @ Wo + bo) -> d_out
        k_agg_fused<128, false><<<NS, 512, 0, stream>>>(hb2_f, es2_f, ed2_f, pool_f, cursor_f,
                                                        b2, g2, be2, Wo, nullptr, nullptr, bo,
                                                        nullptr, nullptr, nullptr,
                                                        (float*)d_out, N);
        return;
    }

    // ---------- fallback: unfused pooled / CSR paths ----------
    unsigned* hb   = (unsigned*)d_ws;                       // [N*128]
    float* h_small = (float*)(hb + (size_t)N * 128);        // [N,64]
    float* es      = h_small + (size_t)N * 64;              // [N,4]
    float* ed      = es + (size_t)N * 4;                    // [N,4]
    int* tail      = (int*)(ed + (size_t)N * 4);

    size_t prefix_bytes = (size_t)((char*)tail - (char*)d_ws);
    size_t pool_need = prefix_bytes + (size_t)NS * POOLCAP * 4 + (size_t)NS * 4;

    unsigned* pool = (unsigned*)tail;
    int* cursor = (int*)(pool + (size_t)NS * POOLCAP);

    int* rowstart = nullptr; int* colarr = nullptr;
    bool pooled = (ws_size >= pool_need) && (NS <= MAX_NS);

    if (pooled) {
        hipMemsetAsync(cursor, 0, (size_t)NS * 4, stream);
        k_bin<<<(E + BIN_EPB - 1) / BIN_EPB, 256, 0, stream>>>(srcp, dstp, cursor, pool, E, NS);
    } else {
        int* deg  = tail;
        rowstart  = deg + N;
        int* cur  = rowstart + (N + 1);
        colarr    = cur + N;
        int* bsum = colarr + (size_t)(E + N);
        k_init_deg<<<nb, 256, 0, stream>>>(deg, N);
        k_count<<<(E + 255) / 256, 256, 0, stream>>>(dstp, deg, E);
        k_scan1<<<nb, 256, 0, stream>>>(deg, rowstart, bsum, N);
        k_scan2<<<1, 256, 0, stream>>>(bsum, nb);
        k_scan3<<<nb, 256, 0, stream>>>(rowstart, cur, bsum, N, E + N);
        k_scatter<<<(E + N + 255) / 256, 256, 0, stream>>>(srcp, dstp, cur, colarr, E, N);
    }

    k_gemm_gat<128><<<dim3(mt128, 2), 256, 0, stream>>>(x, W1, asrc1, adst1,
                                                        (unsigned short*)hb, es, ed, N);
    if (pooled)
        k_agg_sliced<<<NS, 512, 0, stream>>>(hb, es, ed, pool, cursor, b1, g1, be1, h_small, N);
    else
        k_gat_aggregate<<<nwb, 256, 0, stream>>>(hb, es, ed, rowstart, colarr, b1, g1, be1, h_small, N);

    k_gemm_gat<64><<<dim3(mt128, 2), 256, 0, stream>>>(h_small, W2, asrc2, adst2,
                                                       (unsigned short*)hb, es, ed, N);
    if (pooled)
        k_agg_sliced<<<NS, 512, 0, stream>>>(hb, es, ed, pool, cursor, b2, g2, be2, h_small, N);
    else
        k_gat_aggregate<<<nwb, 256, 0, stream>>>(hb, es, ed, rowstart, colarr, b2, g2, be2, h_small, N);

    k_gemm<<<mt128, 256, 0, stream>>>(h_small, Wo, bo, (float*)d_out, N, 128, 64);
}